// Round 1
// 237.638 us; speedup vs baseline: 1.0957x; 1.0957x over previous
//
#include <hip/hip_runtime.h>
#include <hip/hip_bf16.h>
#include <cstdint>
#include <cstddef>

#define AS1 __attribute__((address_space(1)))
#define AS3 __attribute__((address_space(3)))

typedef __bf16 bf16;
typedef __bf16 bf16x8 __attribute__((ext_vector_type(8)));
typedef float f32x4 __attribute__((ext_vector_type(4)));

static constexpr int M_ROWS = 4096;
static constexpr int N_COLS = 1024;
static constexpr int IN_F   = 1024;
static constexpr int K2     = IN_F * 9;   // 9216: [silu(x) | 8 bases per i]
static constexpr int BK     = 32;         // fallback K-step
static constexpr int KT_CNT = K2 / BK;    // 288 (fallback)

static constexpr int GBK = 64;            // gemm K-step: rows are 128 B = 32 banks
static constexpr int GKT = K2 / GBK;      // 144

// Interface (R8 beacon): inputs f32, dict order, sizes in elements, out f32.

// Closed-form cardinal cubic B-spline over uniform knots t[j] = -2.2 + 0.4*j.
__device__ __forceinline__ void bases8(float x, float w8[8]) {
  float mf = x * 2.5f + 5.5f;           // (x - t0) / h
  int   m  = (int)floorf(mf);
  float u  = mf - (float)m;
  float u2 = u * u, u3 = u2 * u;
  float omu = 1.0f - u;
  const float s = 1.0f / 6.0f;
  float p0 = u3 * s;
  float p1 = (-3.f*u3 + 3.f*u2 + 3.f*u + 1.f) * s;
  float p2 = (3.f*u3 - 6.f*u2 + 4.f) * s;
  float p3 = omu * omu * omu * s;
  bool in = (m >= 0) && (m < 11);
#pragma unroll
  for (int j = 0; j < 8; ++j) {
    float v = 0.0f;
    v = (j == m)     ? p0 : v;
    v = (j == m - 1) ? p1 : v;
    v = (j == m - 2) ? p2 : v;
    v = (j == m - 3) ? p3 : v;
    w8[j] = in ? v : 0.0f;
  }
}

// ---------------------------------------------------------------------------
// Kernel 1: A[b,0:1024]=silu(x); A[b,1024+i*8+j]=basis_j(x[b,i]).
// ---------------------------------------------------------------------------
__global__ void expand_a(const float* __restrict__ x, bf16* __restrict__ A,
                         int r0) {
  int gid = blockIdx.x * blockDim.x + threadIdx.x;
  int b = gid >> 10;
  int i = gid & 1023;
  float xv = x[(size_t)r0 * IN_F + (size_t)gid];

  A[(size_t)b * K2 + i] = (bf16)(xv / (1.0f + __expf(-xv)));

  float w8[8];
  bases8(xv, w8);
  bf16x8 outv;
#pragma unroll
  for (int j = 0; j < 8; ++j) outv[j] = (bf16)w8[j];
  *(bf16x8*)(A + (size_t)b * K2 + IN_F + (size_t)i * 8) = outv;
}

// ---------------------------------------------------------------------------
// Kernel 2: BT[o,0:1024]=bw[o,:]; BT[o,1024+i*8+j]=sw[o,i,j]*sc[o,i].
// ---------------------------------------------------------------------------
__global__ void make_bt(const float* __restrict__ bw, const float* __restrict__ sw,
                        const float* __restrict__ sc, bf16* __restrict__ BT) {
  int gid = blockIdx.x * blockDim.x + threadIdx.x;
  int o = gid >> 10;
  int i = gid & 1023;

  BT[(size_t)o * K2 + i] = (bf16)bw[gid];

  float scale = sc[gid];
  const float4* swp = (const float4*)(sw + (size_t)gid * 8);
  float4 a = swp[0], b4 = swp[1];
  float wv[8] = {a.x, a.y, a.z, a.w, b4.x, b4.y, b4.z, b4.w};
  bf16x8 r;
#pragma unroll
  for (int j = 0; j < 8; ++j) r[j] = (bf16)(wv[j] * scale);
  *(bf16x8*)(BT + (size_t)o * K2 + IN_F + (size_t)i * 8) = r;
}

// ---------------------------------------------------------------------------
// Kernel 3 (R12 rewrite): out = A @ BT^T.
//   - 128(M) x 128(N) block, 4 waves as 2x2, wave tile 64x64 (acc 4x4 f32x4).
//     LDS fragment traffic = 2*K2*M*N*(1/64+1/64) = 2.42 GB (was 3.63 GB).
//   - GBK=64: rows are 128 B = all 32 banks. XOR swizzle chunk^=(row&7) on
//     BOTH sides (pre-swizzled global_load_lds source + swizzled ds_read):
//     within any 16-lane quarter, r&7 spans all 8 chunk slots twice ->
//     2 lanes/bank = free (m136). R11's (q^(r&3)) left 4-way = the measured
//     14.16M conflict cycles (4.0 cy per b128 read).
//   - 4-buffer depth-2 pipeline, counted vmcnt: per iter
//     stage(kt+2) -> s_waitcnt vmcnt(16) -> s_barrier -> ds_read+MFMA.
//     One barrier/iter, never vmcnt(0) in steady state. WAR-safe: buffer
//     (kt+2)&3 was last read at iter kt-2; barrier(kt-1) separates.
//   - Grid 256 = 1 block/CU; col0 = (bid&7)*128 pins each 2.36 MB BT panel
//     to one XCD's L2 (8 panels, 8 XCDs).
// ---------------------------------------------------------------------------
__global__ __launch_bounds__(256, 1) void gemm_fused(
    const bf16* __restrict__ A, const bf16* __restrict__ BT,
    float* __restrict__ out, int r0) {
  __shared__ bf16 As[4][128 * GBK];   // 4 x 16 KB
  __shared__ bf16 Bs[4][128 * GBK];   // 4 x 16 KB  (128 KB total)

  const int tid  = threadIdx.x;
  const int lane = tid & 63;
  const int w    = tid >> 6;
  const int row0 = (blockIdx.x >> 3) * 128;   // M base (slab-local)
  const int col0 = (blockIdx.x & 7) * 128;    // N base -> XCD-pinned

  // Staging: per global_load_lds instr a wave writes 8 rows x 128 B linearly;
  // lane l covers (row = l>>3, lds_chunk = l&7). Source chunk = (l&7)^(l>>3)
  // so LDS chunk j of row R holds global chunk j^(R&7).
  const int srow = lane >> 3;
  const int sch  = ((lane & 7) ^ srow) * 8;   // element offset of 16B chunk

  // Fragment reads: row = <base>+r, logical chunk c = kk*4+q, read chunk c^(r&7).
  const int r  = lane & 15;
  const int q  = lane >> 4;
  const int wm = (w >> 1) * 64;
  const int wn = (w & 1) * 64;
  const int kc0 = ((0 + q) ^ (r & 7)) * 8;
  const int kc1 = ((4 + q) ^ (r & 7)) * 8;

  const bf16* aB = A  + (size_t)row0 * K2;
  const bf16* bB = BT + (size_t)col0 * K2;

  f32x4 acc[4][4];
#pragma unroll
  for (int mt = 0; mt < 4; ++mt)
#pragma unroll
    for (int nt = 0; nt < 4; ++nt)
      acc[mt][nt] = f32x4{0.f, 0.f, 0.f, 0.f};

  // Per iter each wave issues 8 global_load_lds (4 A-rowgroups + 4 B-rowgroups
  // of 8 rows each): wave w owns rows [w*32, w*32+32) of both tiles.
  auto stage = [&](int sbuf, int kt) {
#pragma unroll
    for (int t = 0; t < 4; ++t) {
      const int rg = w * 32 + t * 8;
      const bf16* ga = aB + (size_t)(rg + srow) * K2 + kt * GBK + sch;
      __builtin_amdgcn_global_load_lds((const AS1 void*)ga,
                                       (AS3 void*)&As[sbuf][rg * GBK], 16, 0, 0);
      const bf16* gb = bB + (size_t)(rg + srow) * K2 + kt * GBK + sch;
      __builtin_amdgcn_global_load_lds((const AS1 void*)gb,
                                       (AS3 void*)&Bs[sbuf][rg * GBK], 16, 0, 0);
    }
  };

  stage(0, 0);
  stage(1, 1);

  for (int kt = 0; kt < GKT; ++kt) {
    if (kt + 2 < GKT) {
      stage((kt + 2) & 3, kt + 2);
      // Outstanding newer loads: (kt+1)'s 8 + (kt+2)'s 8 -> wait kt's.
      asm volatile("s_waitcnt vmcnt(16)" ::: "memory");
    } else if (kt + 2 == GKT) {
      asm volatile("s_waitcnt vmcnt(8)" ::: "memory");
    } else {
      asm volatile("s_waitcnt vmcnt(0)" ::: "memory");
    }
    __builtin_amdgcn_s_barrier();
    __builtin_amdgcn_sched_barrier(0);

    const bf16* as = As[kt & 3];
    const bf16* bs = Bs[kt & 3];

#pragma unroll
    for (int kk = 0; kk < 2; ++kk) {
      const int kc = kk ? kc1 : kc0;
      bf16x8 af[4], bfr[4];
#pragma unroll
      for (int mt = 0; mt < 4; ++mt)
        af[mt] = *(const bf16x8*)&as[(wm + mt * 16 + r) * GBK + kc];
#pragma unroll
      for (int nt = 0; nt < 4; ++nt)
        bfr[nt] = *(const bf16x8*)&bs[(wn + nt * 16 + r) * GBK + kc];
#pragma unroll
      for (int mt = 0; mt < 4; ++mt)
#pragma unroll
        for (int nt = 0; nt < 4; ++nt)
          acc[mt][nt] = __builtin_amdgcn_mfma_f32_16x16x32_bf16(
              af[mt], bfr[nt], acc[mt][nt], 0, 0, 0);
    }
  }

  // f32 epilogue: C/D layout col = lane&15, row = (lane>>4)*4 + reg
#pragma unroll
  for (int mt = 0; mt < 4; ++mt)
#pragma unroll
    for (int nt = 0; nt < 4; ++nt)
#pragma unroll
      for (int k = 0; k < 4; ++k) {
        int row = r0 + row0 + wm + mt * 16 + q * 4 + k;
        int col = col0 + wn + nt * 16 + r;
        out[(size_t)row * N_COLS + col] = acc[mt][nt][k];
      }
}

// ---------------------------------------------------------------------------
// Fallback (ws too small — not expected; SL=4096 confirmed in R9/R10).
// ---------------------------------------------------------------------------
__global__ __launch_bounds__(256) void kan_fused_fallback(
    const float* __restrict__ x, const float* __restrict__ bw,
    const float* __restrict__ sw, const float* __restrict__ sc,
    float* __restrict__ out) {
  __shared__ bf16 As[64 * BK];
  __shared__ bf16 Bs[128 * BK];
  const int tid  = threadIdx.x;
  const int lane = tid & 63;
  const int w    = tid >> 6;
  const int col0 = blockIdx.x * 128;
  const int row0 = blockIdx.y * 64;
  const int srow = tid >> 2, sq = tid & 3;
  const int r = lane & 15, q = lane >> 4, wn = w * 32;

  f32x4 acc[4][2];
#pragma unroll
  for (int mt = 0; mt < 4; ++mt)
#pragma unroll
    for (int nt = 0; nt < 2; ++nt) acc[mt][nt] = f32x4{0,0,0,0};

  for (int kt = 0; kt < KT_CNT; ++kt) {
    if (kt < 32) {
      const int cc = sq * 8;
      const float4* xp = (const float4*)(x + (size_t)(row0+srow)*IN_F + kt*BK + cc);
      float4 a = xp[0], b4 = xp[1];
      float xv[8] = {a.x,a.y,a.z,a.w,b4.x,b4.y,b4.z,b4.w};
      bf16x8 av;
#pragma unroll
      for (int j = 0; j < 8; ++j) av[j] = (bf16)(xv[j] / (1.0f + __expf(-xv[j])));
      *(bf16x8*)&As[srow * BK + cc] = av;
#pragma unroll
      for (int h = 0; h < 2; ++h) {
        const float4* bp = (const float4*)(bw + (size_t)(col0+h*64+srow)*IN_F + kt*BK + cc);
        float4 c0 = bp[0], c1 = bp[1];
        float bv[8] = {c0.x,c0.y,c0.z,c0.w,c1.x,c1.y,c1.z,c1.w};
        bf16x8 bb;
#pragma unroll
        for (int j = 0; j < 8; ++j) bb[j] = (bf16)bv[j];
        *(bf16x8*)&Bs[(h*64+srow)*BK + cc] = bb;
      }
    } else {
      const int i = (kt - 32) * 4 + sq;
      float xv = x[(size_t)(row0+srow)*IN_F + i];
      float w8[8]; bases8(xv, w8);
      bf16x8 av;
#pragma unroll
      for (int j = 0; j < 8; ++j) av[j] = (bf16)w8[j];
      *(bf16x8*)&As[srow * BK + sq * 8] = av;
#pragma unroll
      for (int h = 0; h < 2; ++h) {
        const int o = col0 + h*64 + srow;
        float s1 = sc[(size_t)o*IN_F + i];
        const float4* sp = (const float4*)(sw + ((size_t)o*IN_F + i)*8);
        float4 c0 = sp[0], c1 = sp[1];
        float wv[8] = {c0.x,c0.y,c0.z,c0.w,c1.x,c1.y,c1.z,c1.w};
        bf16x8 bb;
#pragma unroll
        for (int j = 0; j < 8; ++j) bb[j] = (bf16)(wv[j]*s1);
        *(bf16x8*)&Bs[(h*64+srow)*BK + sq*8] = bb;
      }
    }
    __syncthreads();
    bf16x8 af[4], bfr[2];
#pragma unroll
    for (int mt = 0; mt < 4; ++mt)
      af[mt] = *(const bf16x8*)&As[(mt*16+r)*BK + q*8];
#pragma unroll
    for (int nt = 0; nt < 2; ++nt)
      bfr[nt] = *(const bf16x8*)&Bs[(wn+nt*16+r)*BK + q*8];
#pragma unroll
    for (int mt = 0; mt < 4; ++mt)
#pragma unroll
      for (int nt = 0; nt < 2; ++nt)
        acc[mt][nt] = __builtin_amdgcn_mfma_f32_16x16x32_bf16(af[mt], bfr[nt], acc[mt][nt], 0,0,0);
    __syncthreads();
  }
#pragma unroll
  for (int mt = 0; mt < 4; ++mt)
#pragma unroll
    for (int nt = 0; nt < 2; ++nt)
#pragma unroll
      for (int k = 0; k < 4; ++k)
        out[(size_t)(row0+mt*16+q*4+k)*N_COLS + col0+wn+nt*16+r] = acc[mt][nt][k];
}

extern "C" void kernel_launch(void* const* d_in, const int* in_sizes, int n_in,
                              void* d_out, int out_size, void* d_ws, size_t ws_size,
                              hipStream_t stream) {
  const float* x    = (const float*)d_in[0];
  const float* bw   = (const float*)d_in[1];
  const float* sw   = (const float*)d_in[2];
  const float* sc   = (const float*)d_in[3];
  float* out = (float*)d_out;

  const size_t BT_BYTES  = (size_t)N_COLS * K2 * sizeof(bf16);  // 18.9 MB
  const size_t ROW_BYTES = (size_t)K2 * sizeof(bf16);           // 18 KB
  int SL = 0;
  for (int cand = 4096; cand >= 128; cand >>= 1)
    if (BT_BYTES + (size_t)cand * ROW_BYTES <= ws_size) { SL = cand; break; }

  if (SL) {
    bf16* BT    = (bf16*)d_ws;
    bf16* Aslab = BT + (size_t)N_COLS * K2;
    make_bt<<<(N_COLS * IN_F) / 256, 256, 0, stream>>>(bw, sw, sc, BT);
    for (int r0 = 0; r0 < M_ROWS; r0 += SL) {
      expand_a<<<(SL * IN_F) / 256, 256, 0, stream>>>(x, Aslab, r0);
      // 1-D grid, XCD-pinned column decode: bid&7 = N-panel, bid>>3 = M-tile.
      gemm_fused<<<(SL / 128) * (N_COLS / 128), 256, 0, stream>>>(Aslab, BT, out, r0);
    }
  } else {
    kan_fused_fallback<<<dim3(N_COLS / 128, M_ROWS / 64), 256, 0, stream>>>(
        x, bw, sw, sc, out);
  }
  (void)in_sizes; (void)n_in; (void)out_size;
}

// Round 2
// 204.429 us; speedup vs baseline: 1.2737x; 1.1624x over previous
//
#include <hip/hip_runtime.h>
#include <hip/hip_bf16.h>
#include <cstdint>
#include <cstddef>

#define AS1 __attribute__((address_space(1)))
#define AS3 __attribute__((address_space(3)))

typedef __bf16 bf16;
typedef __bf16 bf16x8 __attribute__((ext_vector_type(8)));
typedef float f32x4 __attribute__((ext_vector_type(4)));

static constexpr int M_ROWS = 4096;
static constexpr int N_COLS = 1024;
static constexpr int IN_F   = 1024;
static constexpr int K2     = IN_F * 9;   // 9216: [silu(x) | 8 bases per i]
static constexpr int BK     = 32;         // fallback K-step
static constexpr int KT_CNT = K2 / BK;    // 288 (fallback)

static constexpr int GBK = 64;            // gemm K-step: rows are 128 B = 32 banks
static constexpr int GKT = K2 / GBK;      // 144

// Interface (R8 beacon): inputs f32, dict order, sizes in elements, out f32.

// Closed-form cardinal cubic B-spline over uniform knots t[j] = -2.2 + 0.4*j.
__device__ __forceinline__ void bases8(float x, float w8[8]) {
  float mf = x * 2.5f + 5.5f;           // (x - t0) / h
  int   m  = (int)floorf(mf);
  float u  = mf - (float)m;
  float u2 = u * u, u3 = u2 * u;
  float omu = 1.0f - u;
  const float s = 1.0f / 6.0f;
  float p0 = u3 * s;
  float p1 = (-3.f*u3 + 3.f*u2 + 3.f*u + 1.f) * s;
  float p2 = (3.f*u3 - 6.f*u2 + 4.f) * s;
  float p3 = omu * omu * omu * s;
  bool in = (m >= 0) && (m < 11);
#pragma unroll
  for (int j = 0; j < 8; ++j) {
    float v = 0.0f;
    v = (j == m)     ? p0 : v;
    v = (j == m - 1) ? p1 : v;
    v = (j == m - 2) ? p2 : v;
    v = (j == m - 3) ? p3 : v;
    w8[j] = in ? v : 0.0f;
  }
}

// ---------------------------------------------------------------------------
// Kernel 1: A[b,0:1024]=silu(x); A[b,1024+i*8+j]=basis_j(x[b,i]).
// ---------------------------------------------------------------------------
__global__ void expand_a(const float* __restrict__ x, bf16* __restrict__ A,
                         int r0) {
  int gid = blockIdx.x * blockDim.x + threadIdx.x;
  int b = gid >> 10;
  int i = gid & 1023;
  float xv = x[(size_t)r0 * IN_F + (size_t)gid];

  A[(size_t)b * K2 + i] = (bf16)(xv / (1.0f + __expf(-xv)));

  float w8[8];
  bases8(xv, w8);
  bf16x8 outv;
#pragma unroll
  for (int j = 0; j < 8; ++j) outv[j] = (bf16)w8[j];
  *(bf16x8*)(A + (size_t)b * K2 + IN_F + (size_t)i * 8) = outv;
}

// ---------------------------------------------------------------------------
// Kernel 2: BT[o,0:1024]=bw[o,:]; BT[o,1024+i*8+j]=sw[o,i,j]*sc[o,i].
// ---------------------------------------------------------------------------
__global__ void make_bt(const float* __restrict__ bw, const float* __restrict__ sw,
                        const float* __restrict__ sc, bf16* __restrict__ BT) {
  int gid = blockIdx.x * blockDim.x + threadIdx.x;
  int o = gid >> 10;
  int i = gid & 1023;

  BT[(size_t)o * K2 + i] = (bf16)bw[gid];

  float scale = sc[gid];
  const float4* swp = (const float4*)(sw + (size_t)gid * 8);
  float4 a = swp[0], b4 = swp[1];
  float wv[8] = {a.x, a.y, a.z, a.w, b4.x, b4.y, b4.z, b4.w};
  bf16x8 r;
#pragma unroll
  for (int j = 0; j < 8; ++j) r[j] = (bf16)(wv[j] * scale);
  *(bf16x8*)(BT + (size_t)o * K2 + IN_F + (size_t)i * 8) = r;
}

// ---------------------------------------------------------------------------
// Kernel 3 (R13): out = A @ BT^T with optional split-K x2.
//   - 128x128 block, 4 waves 2x2, wave 64x64. Swizzle chunk^=(row&7) kept
//     verbatim from R12 (measured SQ_LDS_BANK_CONFLICT = 0).
//   - 2-buffer ping-pong (64 KB LDS) + __launch_bounds__(256,2) -> 2 blocks/CU
//     co-resident when grid >= 512. Depth-1 prefetch, counted vmcnt(8):
//     issue next tile's 8 loads, wait the 8 oldest (= this tile's), barrier,
//     compute, barrier (WAR fence before the buffer is re-staged next iter).
//   - Split-K x2: seg = bid/256 computes kt in [seg*72, seg*72+72) into f32
//     partial d0/d1; reduce_add sums. Grid 512 = 2 blocks/CU = 8 waves/CU,
//     independent blocks self-stagger (TLP hides stage+barrier stalls).
//   - XCD mapping FIX (R12 fetch 304 MB regression): mtile = b%32 so
//     XCD = bid%8 = mtile%8 -> each XCD owns 4 A-panels x all 8 col-panels:
//     A fetched once per XCD group (9.4 MB/XCD), BT streamed (18.9 MB/XCD).
//     R12's col0=(bid&7)*128 made every XCD stream all 75.5 MB of A.
// ---------------------------------------------------------------------------
__global__ __launch_bounds__(256, 2) void gemm_fused(
    const bf16* __restrict__ A, const bf16* __restrict__ BT,
    float* __restrict__ d0, float* __restrict__ d1,
    int r0, int mt_cnt, int kt_seg) {
  __shared__ bf16 As[2][128 * GBK];   // 2 x 16 KB
  __shared__ bf16 Bs[2][128 * GBK];   // 2 x 16 KB  (64 KB total)

  const int tid  = threadIdx.x;
  const int lane = tid & 63;
  const int w    = tid >> 6;

  const int bps = mt_cnt * 8;               // blocks per K-segment
  int b   = blockIdx.x;
  const int seg = b / bps;
  b -= seg * bps;
  const int row0 = (b % mt_cnt) * 128;      // M base (slab-local)
  const int col0 = (b / mt_cnt) * 128;      // N base
  float* __restrict__ dst = seg ? d1 : d0;
  const int kt0 = seg * kt_seg;

  // Staging: per global_load_lds a wave writes 8 rows x 128 B linearly;
  // lane l covers (row = l>>3, lds_chunk = l&7). Source chunk = (l&7)^(l>>3)
  // so LDS chunk j of row R holds global chunk j^(R&7).
  const int srow = lane >> 3;
  const int sch  = ((lane & 7) ^ srow) * 8;

  // Fragment reads: row = <base>+r, logical chunk c = kk*4+q, read c^(r&7).
  const int r  = lane & 15;
  const int q  = lane >> 4;
  const int wm = (w >> 1) * 64;
  const int wn = (w & 1) * 64;
  const int kc0 = ((0 + q) ^ (r & 7)) * 8;
  const int kc1 = ((4 + q) ^ (r & 7)) * 8;

  const bf16* aB = A  + (size_t)row0 * K2;
  const bf16* bB = BT + (size_t)col0 * K2;

  f32x4 acc[4][4];
#pragma unroll
  for (int mt = 0; mt < 4; ++mt)
#pragma unroll
    for (int nt = 0; nt < 4; ++nt)
      acc[mt][nt] = f32x4{0.f, 0.f, 0.f, 0.f};

  // Per iter each wave issues 8 global_load_lds (4 A-rowgroups + 4 B-rowgroups
  // of 8 rows): wave w owns rows [w*32, w*32+32) of both tiles.
  auto stage = [&](int sbuf, int kt) {
#pragma unroll
    for (int t = 0; t < 4; ++t) {
      const int rg = w * 32 + t * 8;
      const bf16* ga = aB + (size_t)(rg + srow) * K2 + kt * GBK + sch;
      __builtin_amdgcn_global_load_lds((const AS1 void*)ga,
                                       (AS3 void*)&As[sbuf][rg * GBK], 16, 0, 0);
      const bf16* gb = bB + (size_t)(rg + srow) * K2 + kt * GBK + sch;
      __builtin_amdgcn_global_load_lds((const AS1 void*)gb,
                                       (AS3 void*)&Bs[sbuf][rg * GBK], 16, 0, 0);
    }
  };

  stage(0, kt0);
  int buf = 0;
  for (int i = 0; i < kt_seg; ++i) {
    if (i + 1 < kt_seg) {
      stage(buf ^ 1, kt0 + i + 1);
      // Outstanding: this iter's 8 (oldest) + next's 8 -> wait the oldest 8.
      asm volatile("s_waitcnt vmcnt(8)" ::: "memory");
    } else {
      asm volatile("s_waitcnt vmcnt(0)" ::: "memory");
    }
    __builtin_amdgcn_s_barrier();          // all waves' tile-i loads landed
    __builtin_amdgcn_sched_barrier(0);

    const bf16* as = As[buf];
    const bf16* bs = Bs[buf];

#pragma unroll
    for (int kk = 0; kk < 2; ++kk) {
      const int kc = kk ? kc1 : kc0;
      bf16x8 af[4], bfr[4];
#pragma unroll
      for (int mt = 0; mt < 4; ++mt)
        af[mt] = *(const bf16x8*)&as[(wm + mt * 16 + r) * GBK + kc];
#pragma unroll
      for (int nt = 0; nt < 4; ++nt)
        bfr[nt] = *(const bf16x8*)&bs[(wn + nt * 16 + r) * GBK + kc];
#pragma unroll
      for (int mt = 0; mt < 4; ++mt)
#pragma unroll
        for (int nt = 0; nt < 4; ++nt)
          acc[mt][nt] = __builtin_amdgcn_mfma_f32_16x16x32_bf16(
              af[mt], bfr[nt], acc[mt][nt], 0, 0, 0);
    }
    __builtin_amdgcn_s_barrier();          // WAR fence: reads done before
    buf ^= 1;                              // this buffer is re-staged
  }

  // f32 epilogue: C/D layout col = lane&15, row = (lane>>4)*4 + reg
#pragma unroll
  for (int mt = 0; mt < 4; ++mt)
#pragma unroll
    for (int nt = 0; nt < 4; ++nt)
#pragma unroll
      for (int k = 0; k < 4; ++k) {
        int row = r0 + row0 + wm + mt * 16 + q * 4 + k;
        int col = col0 + wn + nt * 16 + r;
        dst[(size_t)row * N_COLS + col] = acc[mt][nt][k];
      }
}

// ---------------------------------------------------------------------------
// Kernel 4: out = p0 + p1 (split-K reduce), f32x4 vectorized.
// ---------------------------------------------------------------------------
__global__ void reduce_add(const float* __restrict__ p0,
                           const float* __restrict__ p1,
                           float* __restrict__ out) {
  int i = blockIdx.x * blockDim.x + threadIdx.x;
  f32x4 a = ((const f32x4*)p0)[i];
  f32x4 b = ((const f32x4*)p1)[i];
  ((f32x4*)out)[i] = a + b;
}

// ---------------------------------------------------------------------------
// Fallback (ws too small — not expected; SL=4096 confirmed in R9/R10).
// ---------------------------------------------------------------------------
__global__ __launch_bounds__(256) void kan_fused_fallback(
    const float* __restrict__ x, const float* __restrict__ bw,
    const float* __restrict__ sw, const float* __restrict__ sc,
    float* __restrict__ out) {
  __shared__ bf16 As[64 * BK];
  __shared__ bf16 Bs[128 * BK];
  const int tid  = threadIdx.x;
  const int lane = tid & 63;
  const int w    = tid >> 6;
  const int col0 = blockIdx.x * 128;
  const int row0 = blockIdx.y * 64;
  const int srow = tid >> 2, sq = tid & 3;
  const int r = lane & 15, q = lane >> 4, wn = w * 32;

  f32x4 acc[4][2];
#pragma unroll
  for (int mt = 0; mt < 4; ++mt)
#pragma unroll
    for (int nt = 0; nt < 2; ++nt) acc[mt][nt] = f32x4{0,0,0,0};

  for (int kt = 0; kt < KT_CNT; ++kt) {
    if (kt < 32) {
      const int cc = sq * 8;
      const float4* xp = (const float4*)(x + (size_t)(row0+srow)*IN_F + kt*BK + cc);
      float4 a = xp[0], b4 = xp[1];
      float xv[8] = {a.x,a.y,a.z,a.w,b4.x,b4.y,b4.z,b4.w};
      bf16x8 av;
#pragma unroll
      for (int j = 0; j < 8; ++j) av[j] = (bf16)(xv[j] / (1.0f + __expf(-xv[j])));
      *(bf16x8*)&As[srow * BK + cc] = av;
#pragma unroll
      for (int h = 0; h < 2; ++h) {
        const float4* bp = (const float4*)(bw + (size_t)(col0+h*64+srow)*IN_F + kt*BK + cc);
        float4 c0 = bp[0], c1 = bp[1];
        float bv[8] = {c0.x,c0.y,c0.z,c0.w,c1.x,c1.y,c1.z,c1.w};
        bf16x8 bb;
#pragma unroll
        for (int j = 0; j < 8; ++j) bb[j] = (bf16)bv[j];
        *(bf16x8*)&Bs[(h*64+srow)*BK + cc] = bb;
      }
    } else {
      const int i = (kt - 32) * 4 + sq;
      float xv = x[(size_t)(row0+srow)*IN_F + i];
      float w8[8]; bases8(xv, w8);
      bf16x8 av;
#pragma unroll
      for (int j = 0; j < 8; ++j) av[j] = (bf16)w8[j];
      *(bf16x8*)&As[srow * BK + sq * 8] = av;
#pragma unroll
      for (int h = 0; h < 2; ++h) {
        const int o = col0 + h*64 + srow;
        float s1 = sc[(size_t)o*IN_F + i];
        const float4* sp = (const float4*)(sw + ((size_t)o*IN_F + i)*8);
        float4 c0 = sp[0], c1 = sp[1];
        float wv[8] = {c0.x,c0.y,c0.z,c0.w,c1.x,c1.y,c1.z,c1.w};
        bf16x8 bb;
#pragma unroll
        for (int j = 0; j < 8; ++j) bb[j] = (bf16)(wv[j]*s1);
        *(bf16x8*)&Bs[(h*64+srow)*BK + sq*8] = bb;
      }
    }
    __syncthreads();
    bf16x8 af[4], bfr[2];
#pragma unroll
    for (int mt = 0; mt < 4; ++mt)
      af[mt] = *(const bf16x8*)&As[(mt*16+r)*BK + q*8];
#pragma unroll
    for (int nt = 0; nt < 2; ++nt)
      bfr[nt] = *(const bf16x8*)&Bs[(wn+nt*16+r)*BK + q*8];
#pragma unroll
    for (int mt = 0; mt < 4; ++mt)
#pragma unroll
      for (int nt = 0; nt < 2; ++nt)
        acc[mt][nt] = __builtin_amdgcn_mfma_f32_16x16x32_bf16(af[mt], bfr[nt], acc[mt][nt], 0,0,0);
    __syncthreads();
  }
#pragma unroll
  for (int mt = 0; mt < 4; ++mt)
#pragma unroll
    for (int nt = 0; nt < 2; ++nt)
#pragma unroll
      for (int k = 0; k < 4; ++k)
        out[(size_t)(row0+mt*16+q*4+k)*N_COLS + col0+wn+nt*16+r] = acc[mt][nt][k];
}

extern "C" void kernel_launch(void* const* d_in, const int* in_sizes, int n_in,
                              void* d_out, int out_size, void* d_ws, size_t ws_size,
                              hipStream_t stream) {
  const float* x    = (const float*)d_in[0];
  const float* bw   = (const float*)d_in[1];
  const float* sw   = (const float*)d_in[2];
  const float* sc   = (const float*)d_in[3];
  float* out = (float*)d_out;

  const size_t BT_BYTES  = (size_t)N_COLS * K2 * sizeof(bf16);   // 18.9 MB
  const size_t ROW_BYTES = (size_t)K2 * sizeof(bf16);            // 18 KB
  const size_t A_BYTES   = (size_t)M_ROWS * ROW_BYTES;           // 75.5 MB
  const size_t OUT_BYTES = (size_t)M_ROWS * N_COLS * sizeof(float); // 16.8 MB

  if (BT_BYTES + A_BYTES + 2 * OUT_BYTES <= ws_size) {
    // Split-K x2 path: one expand, one gemm dispatch (512 blocks, 2/CU),
    // partials in ws, reduce.
    bf16*  BT    = (bf16*)d_ws;
    bf16*  Aslab = BT + (size_t)N_COLS * K2;
    float* P0    = (float*)((char*)d_ws + BT_BYTES + A_BYTES);
    float* P1    = P0 + (size_t)M_ROWS * N_COLS;
    make_bt<<<(N_COLS * IN_F) / 256, 256, 0, stream>>>(bw, sw, sc, BT);
    expand_a<<<(M_ROWS * IN_F) / 256, 256, 0, stream>>>(x, Aslab, 0);
    gemm_fused<<<2 * (M_ROWS / 128) * (N_COLS / 128), 256, 0, stream>>>(
        Aslab, BT, P0, P1, 0, M_ROWS / 128, GKT / 2);
    reduce_add<<<(M_ROWS * N_COLS) / (4 * 256), 256, 0, stream>>>(P0, P1, out);
  } else {
    int SL = 0;
    for (int cand = 4096; cand >= 128; cand >>= 1)
      if (BT_BYTES + (size_t)cand * ROW_BYTES <= ws_size) { SL = cand; break; }
    if (SL) {
      bf16* BT    = (bf16*)d_ws;
      bf16* Aslab = BT + (size_t)N_COLS * K2;
      make_bt<<<(N_COLS * IN_F) / 256, 256, 0, stream>>>(bw, sw, sc, BT);
      for (int r0 = 0; r0 < M_ROWS; r0 += SL) {
        expand_a<<<(SL * IN_F) / 256, 256, 0, stream>>>(x, Aslab, r0);
        gemm_fused<<<(SL / 128) * (N_COLS / 128), 256, 0, stream>>>(
            Aslab, BT, out, out, r0, SL / 128, GKT);
      }
    } else {
      kan_fused_fallback<<<dim3(N_COLS / 128, M_ROWS / 64), 256, 0, stream>>>(
          x, bw, sw, sc, out);
    }
  }
  (void)in_sizes; (void)n_in; (void)out_size;
}